// Round 12
// baseline (1006.470 us; speedup 1.0000x reference)
//
#include <hip/hip_runtime.h>
#include <hip/hip_bf16.h>
#include <cstdint>

// ---------------------------------------------------------------------------
// KAN 2-layer forward as two bf16 MFMA GEMMs (fp32 output).
// Round-12 (vs r11 @1000us):
//  * FUSE expand1 into gemm0's epilogue (ws-gated, fallback = r11 path):
//    gemm0 holds h1 = acc+bias in fp32 registers; per 16-row slice it
//    transposes through LDS (free after main loop; padded 9-float chunks ->
//    conflict-free), expands basis/silu, and stores Aug1 short8 chunks
//    (32 lanes x 16B = 512B contiguous per channel). Deletes the expand1
//    dispatch + h1 write (64MB) + h1 read (67MB). Bit-identical numerics
//    (same fp32 h1 -> same basis -> same bf16 rounding): absmax must stay
//    exactly 0.203125.
//  * GEMM main loop/schedule/swizzles FROZEN from r11 (three schedule
//    variants all ~990 TF; schedule is not the binder here).
// ws fused: W [0,40MiB) | Aug0 [40MiB,+151MB) | Aug1 [192937984,+302MB)
//   -> needs ws >= 494,927,872 B. Fallback ws: h1[0,64Mi) W[64,100Mi) Aug[100Mi..).
// ---------------------------------------------------------------------------

typedef __attribute__((ext_vector_type(8))) short short8;
typedef __attribute__((ext_vector_type(4))) short short4v;
typedef __attribute__((ext_vector_type(4))) float f32x4;

#define GLD16(gp, lp)                                                          \
  __builtin_amdgcn_global_load_lds(                                           \
      (const __attribute__((address_space(1))) unsigned int*)(gp),             \
      (__attribute__((address_space(3))) unsigned int*)(lp), 16, 0, 0)

__device__ __forceinline__ unsigned short f2bf(float f) {
  __hip_bfloat16 h = __float2bfloat16(f);
  return *reinterpret_cast<unsigned short*>(&h);
}

__device__ __forceinline__ void basis8(float x, float* w, int& j) {
  float u  = (x + 2.2f) * 2.5f;
  float fj = floorf(u);
  j = (int)fj;
  float t  = u - fj;
  float omt = 1.0f - t;
  float t2 = t * t, t3 = t2 * t;
  w[0] = omt * omt * omt * (1.0f / 6.0f);                              // d==3
  w[1] = (3.0f * t3 - 6.0f * t2 + 4.0f) * (1.0f / 6.0f);               // d==2
  w[2] = (-3.0f * t3 + 3.0f * t2 + 3.0f * t + 1.0f) * (1.0f / 6.0f);   // d==1
  w[3] = t3 * (1.0f / 6.0f);                                           // d==0
}

// ---- pack weights: W[o, kperm(c,i)], kperm = (i/64)*576 + c*64 + (i%64) ----
__global__ void prep_w(const float* __restrict__ coef, const float* __restrict__ sb,
                       const float* __restrict__ sp, const float* __restrict__ mask,
                       __hip_bfloat16* __restrict__ W, int O, int I) {
  long idx = (long)blockIdx.x * blockDim.x + threadIdx.x;
  long total = (long)O * (I >> 2);
  if (idx >= total) return;
  int qtr = I >> 2;
  int iq = (int)(idx % qtr);
  int o  = (int)(idx / qtr);
  int i  = iq << 2;
  size_t oi = (size_t)o * I + i;
  float4 mk4 = *(const float4*)(mask + oi);
  float4 sp4 = *(const float4*)(sp + oi);
  float4 sb4 = *(const float4*)(sb + oi);
  float spm[4] = {sp4.x * mk4.x, sp4.y * mk4.y, sp4.z * mk4.z, sp4.w * mk4.w};
  float cf[4][8];
  const float4* cp = (const float4*)(coef + oi * 8);
#pragma unroll
  for (int e = 0; e < 4; e++) {
    float4 a = cp[e * 2], b = cp[e * 2 + 1];
    cf[e][0] = a.x; cf[e][1] = a.y; cf[e][2] = a.z; cf[e][3] = a.w;
    cf[e][4] = b.x; cf[e][5] = b.y; cf[e][6] = b.z; cf[e][7] = b.w;
  }
  __hip_bfloat16* base = W + (size_t)o * (size_t)(9 * I) + (i >> 6) * 576 + (i & 63);
#pragma unroll
  for (int c = 0; c < 8; c++) {
    short4v pk;
#pragma unroll
    for (int e = 0; e < 4; e++) pk[e] = (short)f2bf(cf[e][c] * spm[e]);
    *(short4v*)(base + c * 64) = pk;
  }
  short4v ps;
  ps[0] = (short)f2bf(sb4.x * mk4.x); ps[1] = (short)f2bf(sb4.y * mk4.y);
  ps[2] = (short)f2bf(sb4.z * mk4.z); ps[3] = (short)f2bf(sb4.w * mk4.w);
  *(short4v*)(base + 8 * 64) = ps;
}

// ---- expand activations: Aug[b, kperm(c,i)], 8 elems/thread ---------------
__global__ void expand_aug(const float* __restrict__ src,
                           __hip_bfloat16* __restrict__ aug,
                           long totalOcts, int I) {
  long idx = (long)blockIdx.x * blockDim.x + threadIdx.x;
  if (idx >= totalOcts) return;
  int  oct = I >> 3;
  int  io = (int)(idx % oct);
  long b  = idx / oct;
  int  i  = io << 3;
  const float* sp = src + b * (size_t)I + i;
  float4 xa = *(const float4*)sp;
  float4 xb = *(const float4*)(sp + 4);
  float xv[8] = {xa.x, xa.y, xa.z, xa.w, xb.x, xb.y, xb.z, xb.w};

  float w[8][4], s[8];
  int   j[8];
#pragma unroll
  for (int e = 0; e < 8; e++) {
    float xe = xv[e];
    s[e] = xe / (1.0f + __expf(-xe));
    basis8(xe, w[e], j[e]);
  }

  __hip_bfloat16* base = aug + b * (size_t)(9 * I) + (i >> 6) * 576 + (i & 63);
#pragma unroll
  for (int c = 0; c < 8; c++) {
    short8 pk;
#pragma unroll
    for (int e = 0; e < 8; e++) {
      int d = j[e] - c;
      float v = 0.0f;
      v = (d == 0) ? w[e][3] : v;
      v = (d == 1) ? w[e][2] : v;
      v = (d == 2) ? w[e][1] : v;
      v = (d == 3) ? w[e][0] : v;
      pk[e] = (short)f2bf(v);
    }
    *(short8*)(base + c * 64) = pk;
  }
  short8 ps;
#pragma unroll
  for (int e = 0; e < 8; e++) ps[e] = (short)f2bf(s[e]);
  *(short8*)(base + 8 * 64) = ps;
}

// ---- phased GEMM (r11 schedule, frozen): C = A*Bw^T + bias ----------------
// BM=256 x BN, BK=32, 8 waves 2Mx4N, 3 bufs, counted vmcnt, 0-conflict
// swizzle both-sides. FUSE: epilogue expands C into AugOut (kperm-64)
// instead of writing C.
template <int BN, bool FUSE>
__global__ __launch_bounds__(512, 2) void gemmP(
    const __hip_bfloat16* __restrict__ A, const __hip_bfloat16* __restrict__ Bw,
    const float* __restrict__ bias, float* __restrict__ Cout, int N, int K,
    __hip_bfloat16* __restrict__ AugOut, int NIout) {
  constexpr int WN   = BN / 4;
  constexpr int NREP = BN / 64;
  constexpr int BUFB = 16384 + BN * 64;
  __shared__ __attribute__((aligned(16))) char lds[3 * BUFB];

  const int t = threadIdx.x;
  const int w = t >> 6, l = t & 63;
  const int wr = w >> 2, wc = w & 3;
  const int lr = l & 15;
  const int kbs = ((l >> 4) * 16) ^ (((lr >> 1) & 3) << 4);

  unsigned nwg = gridDim.x * gridDim.y;
  unsigned lin = blockIdx.y * gridDim.x + blockIdx.x;
  unsigned swz = (lin & 7) * (nwg >> 3) + (lin >> 3);
  unsigned bx = swz % gridDim.x, by = swz / gridDim.x;
  size_t brow = (size_t)by * 256, bcol = (size_t)bx * BN;

  f32x4 acc[8][NREP];
#pragma unroll
  for (int m = 0; m < 8; m++)
#pragma unroll
    for (int n = 0; n < NREP; n++) acc[m][n] = (f32x4){0.f, 0.f, 0.f, 0.f};

  const int srow  = t >> 2;
  const int scolb = ((t & 3) * 16) ^ (((srow >> 1) & 3) << 4);
  const __hip_bfloat16* gA0 = A + (brow + srow) * (size_t)K + (scolb >> 1);
  const __hip_bfloat16* gA1 = gA0 + (size_t)128 * K;
  const __hip_bfloat16* gB0 = Bw + (bcol + srow) * (size_t)K + (scolb >> 1);
  const __hip_bfloat16* gB1 = gB0 + (size_t)128 * K;

  char* ldsp = (char*)lds;
  const int paOff = (wr * 128 + lr) * 64 + kbs;
  const int pbOff = 16384 + (wc * WN + lr) * 64 + kbs;

  auto SA = [&](int kt, int q) {
    char* bp = ldsp + q * BUFB;
    GLD16(gA0 + (kt << 5), bp + w * 1024);
    GLD16(gA1 + (kt << 5), bp + 8192 + w * 1024);
  };
  auto SB = [&](int kt, int q) {
    char* bp = ldsp + q * BUFB + 16384;
    GLD16(gB0 + (kt << 5), bp + w * 1024);
    if constexpr (BN == 256) GLD16(gB1 + (kt << 5), bp + 8192 + w * 1024);
  };
  auto VMCNT_L = [&]() {
    if constexpr (BN == 256) asm volatile("s_waitcnt vmcnt(4)" ::: "memory");
    else                     asm volatile("s_waitcnt vmcnt(3)" ::: "memory");
  };

  SA(0, 0); SB(0, 0);
  SA(1, 1); SB(1, 1);
  VMCNT_L();
  __builtin_amdgcn_s_barrier();

  const int NT = K >> 5;
  int cur = 0;
  for (int tt = 0; tt < NT; ++tt) {
    int q2 = cur + 2; if (q2 >= 3) q2 -= 3;
    const char* pa = ldsp + cur * BUFB + paOff;
    const char* pb = ldsp + cur * BUFB + pbOff;
    short8 bq[NREP], aq[4];
#pragma unroll
    for (int n = 0; n < NREP; n++) bq[n] = *(const short8*)(pb + n * 1024);
#pragma unroll
    for (int m = 0; m < 4; m++) aq[m] = *(const short8*)(pa + m * 1024);
    if (tt + 2 < NT) SA(tt + 2, q2);
    __builtin_amdgcn_s_barrier();
    asm volatile("s_waitcnt lgkmcnt(0)" ::: "memory");
    __builtin_amdgcn_sched_barrier(0);
    __builtin_amdgcn_s_setprio(1);
#pragma unroll
    for (int m = 0; m < 4; m++)
#pragma unroll
      for (int n = 0; n < NREP; n++)
        acc[m][n] = __builtin_amdgcn_mfma_f32_16x16x32_bf16(aq[m], bq[n], acc[m][n], 0, 0, 0);
    __builtin_amdgcn_s_setprio(0);
    __builtin_amdgcn_s_barrier();
#pragma unroll
    for (int m = 0; m < 4; m++) aq[m] = *(const short8*)(pa + (m + 4) * 1024);
    if (tt + 2 < NT) {
      SB(tt + 2, q2);
      VMCNT_L();
    } else if (tt + 1 < NT) {
      asm volatile("s_waitcnt vmcnt(0)" ::: "memory");
    }
    __builtin_amdgcn_s_barrier();
    asm volatile("s_waitcnt lgkmcnt(0)" ::: "memory");
    __builtin_amdgcn_sched_barrier(0);
    __builtin_amdgcn_s_setprio(1);
#pragma unroll
    for (int m = 0; m < 4; m++)
#pragma unroll
      for (int n = 0; n < NREP; n++)
        acc[m + 4][n] = __builtin_amdgcn_mfma_f32_16x16x32_bf16(aq[m], bq[n], acc[m + 4][n], 0, 0, 0);
    __builtin_amdgcn_s_setprio(0);
    __builtin_amdgcn_s_barrier();
    cur = cur + 1; if (cur == 3) cur = 0;
  }

  const int orow = (l >> 4) << 2;

  if constexpr (!FUSE) {
#pragma unroll
    for (int n = 0; n < NREP; n++) {
      size_t col = bcol + (size_t)wc * WN + n * 16 + lr;
      float bv = bias[col];
#pragma unroll
      for (int m = 0; m < 8; m++) {
        size_t row = brow + (size_t)wr * 128 + m * 16 + orow;
#pragma unroll
        for (int r = 0; r < 4; r++)
          Cout[(row + r) * (size_t)N + col] = acc[m][n][r] + bv;
      }
    }
  } else {
    // ---- fused epilogue: expand h1 = acc+bias into AugOut (kperm-64) ----
    // LDS transpose buffer: per wr-half, [16 rows][32 chunks x (8 flt + 1 pad)]
    // = 16*288 floats (18432 B). Chunk stride 36B -> conflict-free reads.
    float bvn[4];
#pragma unroll
    for (int n = 0; n < 4; n++) bvn[n] = bias[bcol + (size_t)wc * 64 + n * 16 + lr];
    float* tb  = (float*)ldsp + wr * 4608;          // this wave's write half
    const int rowl = t >> 5;                        // 0..15 (read side)
    const int chv  = t & 31;                        // 0..31
    const size_t ostride = (size_t)9 * NIout;
    __builtin_amdgcn_s_barrier();                   // main loop fully done
#pragma unroll
    for (int m = 0; m < 8; m++) {
      // scatter slice m (rows wr*128+m*16+0..15) into transpose buffer
#pragma unroll
      for (int n = 0; n < 4; n++) {
        int colL = wc * 64 + n * 16 + lr;
        int cI = colL >> 3, eI = colL & 7;
#pragma unroll
        for (int r = 0; r < 4; r++)
          tb[(orow + r) * 288 + cI * 9 + eI] = acc[m][n][r] + bvn[n];
      }
      __builtin_amdgcn_s_barrier();
      // gather 8 consecutive i for one row, expand, store
#pragma unroll
      for (int h = 0; h < 2; h++) {
        const float* tb2 = (const float*)ldsp + h * 4608;
        float xv[8];
#pragma unroll
        for (int e = 0; e < 8; e++) xv[e] = tb2[rowl * 288 + chv * 9 + e];
        float wg[8][4], sv[8];
        int   jv[8];
#pragma unroll
        for (int e = 0; e < 8; e++) {
          float xe = xv[e];
          sv[e] = xe / (1.0f + __expf(-xe));
          basis8(xe, wg[e], jv[e]);
        }
        size_t bgl = brow + h * 128 + m * 16 + rowl;
        int ig = (int)bcol + chv * 8;
        __hip_bfloat16* bp = AugOut + bgl * ostride + (ig >> 6) * 576 + (ig & 63);
#pragma unroll
        for (int c = 0; c < 8; c++) {
          short8 pk;
#pragma unroll
          for (int e = 0; e < 8; e++) {
            int d = jv[e] - c;
            float v = 0.0f;
            v = (d == 0) ? wg[e][3] : v;
            v = (d == 1) ? wg[e][2] : v;
            v = (d == 2) ? wg[e][1] : v;
            v = (d == 3) ? wg[e][0] : v;
            pk[e] = (short)f2bf(v);
          }
          *(short8*)(bp + c * 64) = pk;
        }
        short8 ps;
#pragma unroll
        for (int e = 0; e < 8; e++) ps[e] = (short)f2bf(sv[e]);
        *(short8*)(bp + 8 * 64) = ps;
      }
      __builtin_amdgcn_s_barrier();   // before next slice overwrites LDS
    }
  }
}

// ---------------------------------------------------------------------------
extern "C" void kernel_launch(void* const* d_in, const int* in_sizes, int n_in,
                              void* d_out, int out_size, void* d_ws, size_t ws_size,
                              hipStream_t stream) {
  const float* x     = (const float*)d_in[0];
  const float* coef0 = (const float*)d_in[1];
  const float* sb0   = (const float*)d_in[2];
  const float* sp0   = (const float*)d_in[3];
  const float* mask0 = (const float*)d_in[4];
  const float* bias0 = (const float*)d_in[5];
  const float* coef1 = (const float*)d_in[6];
  const float* sb1   = (const float*)d_in[7];
  const float* sp1   = (const float*)d_in[8];
  const float* sp1m  = (const float*)d_in[9];
  const float* bias1 = (const float*)d_in[10];
  const float* mask1 = sp1m;
  float* out = (float*)d_out;

  const int B = 8192, D0 = 1024, D1 = 2048, D2 = 1024;
  const int K0 = 9 * D0;   // 9216
  const int K1 = 9 * D1;   // 18432

  char* ws = (char*)d_ws;
  const bool fused = ws_size >= (size_t)494927872;

  if (fused) {
    __hip_bfloat16* W    = (__hip_bfloat16*)ws;                          // 40 MiB
    __hip_bfloat16* Aug0 = (__hip_bfloat16*)(ws + (size_t)41943040);     // 151 MB
    __hip_bfloat16* Aug1 = (__hip_bfloat16*)(ws + (size_t)192937984);    // 302 MB

    long nt0 = (long)D1 * (D0 / 4);
    prep_w<<<(unsigned)((nt0 + 255) / 256), 256, 0, stream>>>(coef0, sb0, sp0, mask0, W, D1, D0);
    long no0 = (long)B * (D0 / 8);
    expand_aug<<<(unsigned)((no0 + 255) / 256), 256, 0, stream>>>(x, Aug0, no0, D0);
    dim3 g0(D1 / 256, B / 256);  // (8, 32)
    gemmP<256, true><<<g0, 512, 0, stream>>>(Aug0, W, bias0, nullptr, D1, K0, Aug1, D1);

    long nt1 = (long)D2 * (D1 / 4);
    prep_w<<<(unsigned)((nt1 + 255) / 256), 256, 0, stream>>>(coef1, sb1, sp1, mask1, W, D2, D1);
    dim3 g1(D2 / 128, B / 256);  // (8, 32)
    gemmP<128, false><<<g1, 512, 0, stream>>>(Aug1, W, bias1, out, D2, K1, nullptr, 0);
  } else {
    // r11 fallback (proven)
    float*          h1  = (float*)ws;
    __hip_bfloat16* W   = (__hip_bfloat16*)(ws + (size_t)67108864);
    __hip_bfloat16* Aug = (__hip_bfloat16*)(ws + (size_t)104857600);
    const bool fullL1 = ws_size >= (size_t)104857600 + (size_t)B * K1 * 2;

    long nt0 = (long)D1 * (D0 / 4);
    prep_w<<<(unsigned)((nt0 + 255) / 256), 256, 0, stream>>>(coef0, sb0, sp0, mask0, W, D1, D0);
    long no0 = (long)B * (D0 / 8);
    expand_aug<<<(unsigned)((no0 + 255) / 256), 256, 0, stream>>>(x, Aug, no0, D0);
    dim3 g0(D1 / 256, B / 256);
    gemmP<256, false><<<g0, 512, 0, stream>>>(Aug, W, bias0, h1, D1, K0, nullptr, 0);

    long nt1 = (long)D2 * (D1 / 4);
    prep_w<<<(unsigned)((nt1 + 255) / 256), 256, 0, stream>>>(coef1, sb1, sp1, mask1, W, D2, D1);
    const int CH = fullL1 ? B : 4096;
    for (int ch = 0; ch < B / CH; ch++) {
      long no1 = (long)CH * (D1 / 8);
      expand_aug<<<(unsigned)((no1 + 255) / 256), 256, 0, stream>>>(
          h1 + (size_t)ch * CH * D1, Aug, no1, D1);
      dim3 g1(D2 / 128, CH / 256);
      gemmP<128, false><<<g1, 512, 0, stream>>>(Aug, W, bias1,
                                                out + (size_t)ch * CH * D2, D2, K1, nullptr, 0);
    }
  }
}

// Round 15
// 793.278 us; speedup vs baseline: 1.2687x; 1.2687x over previous
//
#include <hip/hip_runtime.h>
#include <hip/hip_bf16.h>
#include <cstdint>

// ---------------------------------------------------------------------------
// KAN 2-layer forward as two bf16 MFMA GEMMs (fp32 output).
// Round-15 (r13/r14 crash root-caused: ws_size < 406.8MB; all fullL1 gates
// rounds 4-12 silently fell back -> L1 always ran chunked at 128 blocks):
//  * ws = r3-PROVEN 255,852,544 B: h1[0,64Mi) | W[64Mi,100Mi) | AugRegion
//    [100Mi,+151MB). W1 overwrites W0 after L0-gemm; Aug1 chunks (CH=4096,
//    exactly 151MB) reuse AugRegion. No gates, no unproven footprint.
//  * GEMM = gemm128 (BM=128, r13's schedule, ws-exonerated): depth-2,
//    3 bufs, counted vmcnt (sim-verified: VM(2L) drains tile kt at iter kt),
//    0-conflict swizzle both-sides, XCD swizzle, setprio.
//    L0: gemm128<256> grid (8,64)=512 blocks (2/CU, 72KB LDS).
//    L1 chunks: gemm128<128> grid (8,32)=256 blocks (2/CU, 48KB LDS) —
//    L1 finally uses the whole GPU (was 128 blocks = half).
//  * aux = r11-proven standalone prep_w / expand_aug (kperm-576).
// ---------------------------------------------------------------------------

typedef __attribute__((ext_vector_type(8))) short short8;
typedef __attribute__((ext_vector_type(4))) short short4v;
typedef __attribute__((ext_vector_type(4))) float f32x4;

#define GLD16(gp, lp)                                                          \
  __builtin_amdgcn_global_load_lds(                                           \
      (const __attribute__((address_space(1))) unsigned int*)(gp),             \
      (__attribute__((address_space(3))) unsigned int*)(lp), 16, 0, 0)

__device__ __forceinline__ unsigned short f2bf(float f) {
  __hip_bfloat16 h = __float2bfloat16(f);
  return *reinterpret_cast<unsigned short*>(&h);
}

__device__ __forceinline__ void basis8(float x, float* w, int& j) {
  float u  = (x + 2.2f) * 2.5f;
  float fj = floorf(u);
  j = (int)fj;
  float t  = u - fj;
  float omt = 1.0f - t;
  float t2 = t * t, t3 = t2 * t;
  w[0] = omt * omt * omt * (1.0f / 6.0f);                              // d==3
  w[1] = (3.0f * t3 - 6.0f * t2 + 4.0f) * (1.0f / 6.0f);               // d==2
  w[2] = (-3.0f * t3 + 3.0f * t2 + 3.0f * t + 1.0f) * (1.0f / 6.0f);   // d==1
  w[3] = t3 * (1.0f / 6.0f);                                           // d==0
}

// ---- pack weights: W[o, kperm(c,i)], kperm = (i/64)*576 + c*64 + (i%64) ----
__global__ void prep_w(const float* __restrict__ coef, const float* __restrict__ sb,
                       const float* __restrict__ sp, const float* __restrict__ mask,
                       __hip_bfloat16* __restrict__ W, int O, int I) {
  long idx = (long)blockIdx.x * blockDim.x + threadIdx.x;
  long total = (long)O * (I >> 2);
  if (idx >= total) return;
  int qtr = I >> 2;
  int iq = (int)(idx % qtr);
  int o  = (int)(idx / qtr);
  int i  = iq << 2;
  size_t oi = (size_t)o * I + i;
  float4 mk4 = *(const float4*)(mask + oi);
  float4 sp4 = *(const float4*)(sp + oi);
  float4 sb4 = *(const float4*)(sb + oi);
  float spm[4] = {sp4.x * mk4.x, sp4.y * mk4.y, sp4.z * mk4.z, sp4.w * mk4.w};
  float cf[4][8];
  const float4* cp = (const float4*)(coef + oi * 8);
#pragma unroll
  for (int e = 0; e < 4; e++) {
    float4 a = cp[e * 2], b = cp[e * 2 + 1];
    cf[e][0] = a.x; cf[e][1] = a.y; cf[e][2] = a.z; cf[e][3] = a.w;
    cf[e][4] = b.x; cf[e][5] = b.y; cf[e][6] = b.z; cf[e][7] = b.w;
  }
  __hip_bfloat16* base = W + (size_t)o * (size_t)(9 * I) + (i >> 6) * 576 + (i & 63);
#pragma unroll
  for (int c = 0; c < 8; c++) {
    short4v pk;
#pragma unroll
    for (int e = 0; e < 4; e++) pk[e] = (short)f2bf(cf[e][c] * spm[e]);
    *(short4v*)(base + c * 64) = pk;
  }
  short4v ps;
  ps[0] = (short)f2bf(sb4.x * mk4.x); ps[1] = (short)f2bf(sb4.y * mk4.y);
  ps[2] = (short)f2bf(sb4.z * mk4.z); ps[3] = (short)f2bf(sb4.w * mk4.w);
  *(short4v*)(base + 8 * 64) = ps;
}

// ---- expand activations: Aug[b, kperm(c,i)], 8 elems/thread ---------------
__global__ void expand_aug(const float* __restrict__ src,
                           __hip_bfloat16* __restrict__ aug,
                           long totalOcts, int I) {
  long idx = (long)blockIdx.x * blockDim.x + threadIdx.x;
  if (idx >= totalOcts) return;
  int  oct = I >> 3;
  int  io = (int)(idx % oct);
  long b  = idx / oct;
  int  i  = io << 3;
  const float* sp = src + b * (size_t)I + i;
  float4 xa = *(const float4*)sp;
  float4 xb = *(const float4*)(sp + 4);
  float xv[8] = {xa.x, xa.y, xa.z, xa.w, xb.x, xb.y, xb.z, xb.w};

  float w[8][4], s[8];
  int   j[8];
#pragma unroll
  for (int e = 0; e < 8; e++) {
    float xe = xv[e];
    s[e] = xe / (1.0f + __expf(-xe));
    basis8(xe, w[e], j[e]);
  }
  __hip_bfloat16* base = aug + b * (size_t)(9 * I) + (i >> 6) * 576 + (i & 63);
#pragma unroll
  for (int c = 0; c < 8; c++) {
    short8 pk;
#pragma unroll
    for (int e = 0; e < 8; e++) {
      int d = j[e] - c;
      float v = 0.0f;
      v = (d == 0) ? w[e][3] : v;
      v = (d == 1) ? w[e][2] : v;
      v = (d == 2) ? w[e][1] : v;
      v = (d == 3) ? w[e][0] : v;
      pk[e] = (short)f2bf(v);
    }
    *(short8*)(base + c * 64) = pk;
  }
  short8 ps;
#pragma unroll
  for (int e = 0; e < 8; e++) ps[e] = (short)f2bf(s[e]);
  *(short8*)(base + 8 * 64) = ps;
}

// ---- 128xBN GEMM, 2 blocks/CU: C = A*Bw^T + bias, fp32 out -----------------
// BM=128, BN 256/128, BK=32, 8 waves 2Mx4N (per-wave 64 x BN/4), 3 buffers.
// LDS/buf: A 8KB + B BN*64B; x3 = 72/48KB -> 2 blocks/CU (launch_bounds 512,4).
// Depth-2 prefetch; vmcnt sim: prologue VM(L) lands tile0; iter kt VM(2L)
// lands tile kt; tails VM(L), VM(0). WAR: STAGE(kt+2)->buf(kt-1) after
// COMPUTE(kt-1)'s closing barrier. 0-conflict swizzle both-sides.
template <int BN>
__global__ __launch_bounds__(512, 4) void gemm128(
    const __hip_bfloat16* __restrict__ A, const __hip_bfloat16* __restrict__ Bw,
    const float* __restrict__ bias, float* __restrict__ Cout, int N, int K) {
  constexpr int WN   = BN / 4;
  constexpr int NREP = BN / 64;
  constexpr int BUFB = 8192 + BN * 64;
  constexpr int L    = 1 + BN / 128;   // GLD16/tile/thread: 3 (256), 2 (128)
  __shared__ __attribute__((aligned(16))) char lds[3 * BUFB];

  const int t = threadIdx.x;
  const int w = t >> 6, l = t & 63;
  const int wr = w >> 2, wc = w & 3;
  const int lr = l & 15;
  const int kbs = ((l >> 4) * 16) ^ (((lr >> 1) & 3) << 4);

  unsigned nwg = gridDim.x * gridDim.y;
  unsigned lin = blockIdx.y * gridDim.x + blockIdx.x;
  unsigned swz = (lin & 7) * (nwg >> 3) + (lin >> 3);
  unsigned bx = swz % gridDim.x, by = swz / gridDim.x;
  size_t brow = (size_t)by * 128, bcol = (size_t)bx * BN;

  f32x4 acc[4][NREP];
#pragma unroll
  for (int m = 0; m < 4; m++)
#pragma unroll
    for (int n = 0; n < NREP; n++) acc[m][n] = (f32x4){0.f, 0.f, 0.f, 0.f};

  const int srow  = t >> 2;                                     // 0..127
  const int scolb = ((t & 3) * 16) ^ (((srow >> 1) & 3) << 4);
  const __hip_bfloat16* gA0 = A + (brow + srow) * (size_t)K + (scolb >> 1);
  const __hip_bfloat16* gB0 = Bw + (bcol + srow) * (size_t)K + (scolb >> 1);
  const __hip_bfloat16* gB1 = gB0 + (size_t)128 * K;            // BN=256 only

  char* ldsp = (char*)lds;
  const int paOff = (wr * 64 + lr) * 64 + kbs;            // + m*1024 + q*BUFB
  const int pbOff = 8192 + (wc * WN + lr) * 64 + kbs;     // + n*1024 + q*BUFB

  auto STAGE = [&](int kt, int q) {
    char* bp = ldsp + q * BUFB;
    GLD16(gA0 + (kt << 5), bp + w * 1024);
    GLD16(gB0 + (kt << 5), bp + 8192 + w * 1024);
    if constexpr (BN == 256) GLD16(gB1 + (kt << 5), bp + 16384 + w * 1024);
  };
  auto COMPUTE = [&](int q) {
    const char* pa = ldsp + q * BUFB + paOff;
    const char* pb = ldsp + q * BUFB + pbOff;
    short8 bq[NREP], aq[4];
#pragma unroll
    for (int n = 0; n < NREP; n++) bq[n] = *(const short8*)(pb + n * 1024);
#pragma unroll
    for (int m = 0; m < 4; m++) aq[m] = *(const short8*)(pa + m * 1024);
    __builtin_amdgcn_s_setprio(1);
#pragma unroll
    for (int m = 0; m < 4; m++)
#pragma unroll
      for (int n = 0; n < NREP; n++)
        acc[m][n] = __builtin_amdgcn_mfma_f32_16x16x32_bf16(aq[m], bq[n], acc[m][n], 0, 0, 0);
    __builtin_amdgcn_s_setprio(0);
    __builtin_amdgcn_s_barrier();   // all waves' reads of buf q retired
  };
  auto VM0 = [&]() { asm volatile("s_waitcnt vmcnt(0)" ::: "memory"); };
  auto VML = [&]() {
    if constexpr (BN == 256) asm volatile("s_waitcnt vmcnt(3)" ::: "memory");
    else                     asm volatile("s_waitcnt vmcnt(2)" ::: "memory");
  };
  auto VM2L = [&]() {
    if constexpr (BN == 256) asm volatile("s_waitcnt vmcnt(6)" ::: "memory");
    else                     asm volatile("s_waitcnt vmcnt(4)" ::: "memory");
  };

  const int NT = K >> 5;   // 288 (L0) / 576 (L1)

  STAGE(0, 0);
  STAGE(1, 1);
  VML();                                  // tile 0 landed
  __builtin_amdgcn_s_barrier();

  int q0 = 0;
  for (int kt = 0; kt < NT - 2; ++kt) {
    int q2 = q0 + 2; if (q2 >= 3) q2 -= 3;
    STAGE(kt + 2, q2);                    // buf of tile kt-1 (reads done)
    VM2L();                               // tile kt landed (oldest drained)
    __builtin_amdgcn_s_barrier();         // publish
    COMPUTE(q0);
    q0 = (q0 == 2) ? 0 : q0 + 1;
  }
  VML();                                  // tile NT-2 landed
  __builtin_amdgcn_s_barrier();
  COMPUTE(q0);
  q0 = (q0 == 2) ? 0 : q0 + 1;
  VM0();                                  // tile NT-1 landed
  __builtin_amdgcn_s_barrier();
  COMPUTE(q0);

  // epilogue
  const int orow = (l >> 4) << 2;
#pragma unroll
  for (int n = 0; n < NREP; n++) {
    size_t col = bcol + (size_t)wc * WN + n * 16 + lr;
    float bv = bias[col];
#pragma unroll
    for (int m = 0; m < 4; m++) {
      size_t row = brow + (size_t)wr * 64 + m * 16 + orow;
#pragma unroll
      for (int r = 0; r < 4; r++)
        Cout[(row + r) * (size_t)N + col] = acc[m][n][r] + bv;
    }
  }
}

// ---------------------------------------------------------------------------
extern "C" void kernel_launch(void* const* d_in, const int* in_sizes, int n_in,
                              void* d_out, int out_size, void* d_ws, size_t ws_size,
                              hipStream_t stream) {
  const float* x     = (const float*)d_in[0];
  const float* coef0 = (const float*)d_in[1];
  const float* sb0   = (const float*)d_in[2];
  const float* sp0   = (const float*)d_in[3];
  const float* mask0 = (const float*)d_in[4];
  const float* bias0 = (const float*)d_in[5];
  const float* coef1 = (const float*)d_in[6];
  const float* sb1   = (const float*)d_in[7];
  const float* sp1   = (const float*)d_in[8];
  const float* mask1 = (const float*)d_in[9];
  const float* bias1 = (const float*)d_in[10];
  float* out = (float*)d_out;

  const int B = 8192, D0 = 1024, D1 = 2048, D2 = 1024;
  const int K0 = 9 * D0;   // 9216
  const int K1 = 9 * D1;   // 18432
  const int CH = 4096;     // L1 batch chunk

  // ws (255,852,544 B total — r3-PROVEN):
  //   h1  [0, 67108864)           8192x2048 fp32
  //   W   [67108864, 104857600)   37,748,736 B (W0, then W1 overwrites)
  //   Aug [104857600, +150994944) Aug0 full / Aug1 chunk (both exactly 151MB)
  char* ws = (char*)d_ws;
  float*          h1  = (float*)ws;
  __hip_bfloat16* W   = (__hip_bfloat16*)(ws + (size_t)67108864);
  __hip_bfloat16* Aug = (__hip_bfloat16*)(ws + (size_t)104857600);

  // ---- layer 0: full batch ----
  {
    long nt = (long)D1 * (D0 / 4);
    prep_w<<<(unsigned)((nt + 255) / 256), 256, 0, stream>>>(coef0, sb0, sp0, mask0, W, D1, D0);
    long no = (long)B * (D0 / 8);
    expand_aug<<<(unsigned)((no + 255) / 256), 256, 0, stream>>>(x, Aug, no, D0);
    dim3 g0(D1 / 256, B / 128);   // (8, 64) = 512 blocks, 2/CU
    gemm128<256><<<g0, 512, 0, stream>>>(Aug, W, bias0, h1, D1, K0);
  }

  // ---- layer 1: 2 chunks of 4096, each on the FULL GPU ----
  {
    long nt = (long)D2 * (D1 / 4);
    prep_w<<<(unsigned)((nt + 255) / 256), 256, 0, stream>>>(coef1, sb1, sp1, mask1, W, D2, D1);
    for (int ch = 0; ch < B / CH; ch++) {
      long no = (long)CH * (D1 / 8);
      expand_aug<<<(unsigned)((no + 255) / 256), 256, 0, stream>>>(
          h1 + (size_t)ch * CH * D1, Aug, no, D1);
      dim3 g1(D2 / 128, CH / 128);   // (8, 32) = 256 blocks, 2/CU
      gemm128<128><<<g1, 512, 0, stream>>>(Aug, W, bias1,
                                           out + (size_t)ch * CH * D2, D2, K1);
    }
  }
}